// Round 10
// baseline (154.161 us; speedup 1.0000x reference)
//
#include <hip/hip_runtime.h>
#include <hip/hip_bf16.h>
#include <cstdint>
#include <cstddef>

#define N_B 4
#define D_F 512
#define L_S 2048
#define H_N 8
#define DH  64
#define C3  (3*D_F)   // 1536

typedef __attribute__((ext_vector_type(8)))  short short8;
typedef __attribute__((ext_vector_type(4)))  float f32x4;
typedef __attribute__((ext_vector_type(16))) float f32x16;

__device__ __forceinline__ unsigned int pk_bf16(float a, float b) {
    __hip_bfloat162 h = __float22bfloat162_rn(float2{a, b});
    union { __hip_bfloat162 h; unsigned int u; } cv;
    cv.h = h;
    return cv.u;
}
__device__ __forceinline__ unsigned short bf16_rn(float f) {
    union { float f; unsigned int u; } c; c.f = f;
    unsigned int r = c.u + 0x7FFF + ((c.u >> 16) & 1);
    return (unsigned short)(r >> 16);
}
__device__ __forceinline__ float bf16_f(unsigned short h) {
    union { unsigned int u; float f; } c; c.u = ((unsigned int)h) << 16;
    return c.f;
}

// async global->LDS, 16B per lane; lds base must be wave-uniform; global addr per-lane.
__device__ __forceinline__ void gll16(const unsigned short* g, unsigned short* l) {
    __builtin_amdgcn_global_load_lds(
        (const __attribute__((address_space(1))) unsigned int*)g,
        (__attribute__((address_space(3))) unsigned int*)l,
        16, 0, 0);
}

// ---------------------------------------------------------------------------
// Split fp32 -> bf16 hi + bf16 lo (weights only)
// ---------------------------------------------------------------------------
__global__ __launch_bounds__(256) void cvt_split(const float* __restrict__ src,
                                                 unsigned short* __restrict__ hi,
                                                 unsigned short* __restrict__ lo,
                                                 int n4) {
    int i = blockIdx.x * 256 + threadIdx.x;
    if (i >= n4) return;
    float4 v = ((const float4*)src)[i];
    ushort4 h, l;
    h.x = bf16_rn(v.x); l.x = bf16_rn(v.x - bf16_f(h.x));
    h.y = bf16_rn(v.y); l.y = bf16_rn(v.y - bf16_f(h.y));
    h.z = bf16_rn(v.z); l.z = bf16_rn(v.z - bf16_f(h.z));
    h.w = bf16_rn(v.w); l.w = bf16_rn(v.w - bf16_f(h.w));
    ((ushort4*)hi)[i] = h;
    ((ushort4*)lo)[i] = l;
}

// ---------------------------------------------------------------------------
// Transpose+convert: x[n][c][l] f32 -> xT[n][l][c] bf16 (unchanged).
// ---------------------------------------------------------------------------
__global__ __launch_bounds__(256) void cvt_xT(const float* __restrict__ x,
                                              unsigned short* __restrict__ xT,
                                              int C) {
    __shared__ float tile[64][65];
    const int tid = threadIdx.x;
    const int l0  = blockIdx.x * 64;
    const int c0  = blockIdx.y * 64;
    const int n   = blockIdx.z;

    const float* xn = x + (size_t)n * C * L_S;
#pragma unroll
    for (int r = 0; r < 16; ++r) {
        int c = r * 4 + (tid >> 6);
        int l = tid & 63;
        tile[c][l] = xn[(size_t)(c0 + c) * L_S + l0 + l];
    }
    __syncthreads();

    unsigned short* xn_t = xT + (size_t)n * L_S * C;
#pragma unroll
    for (int r = 0; r < 8; ++r) {
        int l  = r * 8 + (tid >> 5);
        int cp = tid & 31;
        unsigned int pk = pk_bf16(tile[cp * 2][l], tile[cp * 2 + 1][l]);
        *(unsigned int*)&xn_t[(size_t)(l0 + l) * C + c0 + cp * 2] = pk;
    }
}

// ---------------------------------------------------------------------------
// MFMA GEMM v2 (unchanged from R8).
// ---------------------------------------------------------------------------
template<int SPLIT, int OUT_BF16>
__global__ __launch_bounds__(256) void gemm_mfma2(const unsigned short* __restrict__ Whi,
                                                  const unsigned short* __restrict__ Wlo,
                                                  const unsigned short* __restrict__ XThi,
                                                  const unsigned short* __restrict__ XTlo,
                                                  void* __restrict__ Y,
                                                  int O, int C) {
    __shared__ unsigned short Wt[SPLIT ? 2 : 1][4][128 * 8];
    __shared__ unsigned short Xt[SPLIT ? 2 : 1][4][128 * 8];

    const int tid  = threadIdx.x;
    const int lane = tid & 63;
    const int w    = tid >> 6;
    const int g    = lane >> 4;
    const int c    = lane & 15;
    const int wr   = (w >> 1) * 64;
    const int wc   = (w & 1) * 64;
    const int l0   = blockIdx.x * 128;
    const int o0   = blockIdx.y * 128;
    const int n    = blockIdx.z;

    const unsigned short* XTn_hi = XThi + (size_t)n * L_S * C;
    const unsigned short* XTn_lo = SPLIT ? (XTlo + (size_t)n * L_S * C) : nullptr;

    const int rhalf = (w & 1) * 64;
    const int cpA   = w >> 1;
    const int cpB   = 2 + (w >> 1);
    const size_t wrowA = (size_t)(o0 + rhalf + lane) * C;
    const size_t xrowA = (size_t)(l0 + rhalf + lane) * C;

    f32x4 acc[4][4];
#pragma unroll
    for (int mt = 0; mt < 4; ++mt)
#pragma unroll
        for (int nt = 0; nt < 4; ++nt) acc[mt][nt] = (f32x4){0.f, 0.f, 0.f, 0.f};

    for (int c0 = 0; c0 < C; c0 += 32) {
        __syncthreads();
        gll16(Whi + wrowA + c0 + cpA * 8, &Wt[0][cpA][rhalf * 8]);
        gll16(Whi + wrowA + c0 + cpB * 8, &Wt[0][cpB][rhalf * 8]);
        gll16(XTn_hi + xrowA + c0 + cpA * 8, &Xt[0][cpA][rhalf * 8]);
        gll16(XTn_hi + xrowA + c0 + cpB * 8, &Xt[0][cpB][rhalf * 8]);
        if (SPLIT) {
            gll16(Wlo + wrowA + c0 + cpA * 8, &Wt[1][cpA][rhalf * 8]);
            gll16(Wlo + wrowA + c0 + cpB * 8, &Wt[1][cpB][rhalf * 8]);
            gll16(XTn_lo + xrowA + c0 + cpA * 8, &Xt[1][cpA][rhalf * 8]);
            gll16(XTn_lo + xrowA + c0 + cpB * 8, &Xt[1][cpB][rhalf * 8]);
        }
        __syncthreads();

        short8 a0[4], b0[4];
#pragma unroll
        for (int mt = 0; mt < 4; ++mt) a0[mt] = *(short8*)&Wt[0][g][(wr + mt * 16 + c) * 8];
#pragma unroll
        for (int nt = 0; nt < 4; ++nt) b0[nt] = *(short8*)&Xt[0][g][(wc + nt * 16 + c) * 8];

        if (SPLIT) {
            short8 a1[4], b1[4];
#pragma unroll
            for (int mt = 0; mt < 4; ++mt) a1[mt] = *(short8*)&Wt[1][g][(wr + mt * 16 + c) * 8];
#pragma unroll
            for (int nt = 0; nt < 4; ++nt) b1[nt] = *(short8*)&Xt[1][g][(wc + nt * 16 + c) * 8];
#pragma unroll
            for (int mt = 0; mt < 4; ++mt)
#pragma unroll
                for (int nt = 0; nt < 4; ++nt) {
                    acc[mt][nt] = __builtin_amdgcn_mfma_f32_16x16x32_bf16(a0[mt], b0[nt], acc[mt][nt], 0, 0, 0);
                    acc[mt][nt] = __builtin_amdgcn_mfma_f32_16x16x32_bf16(a0[mt], b1[nt], acc[mt][nt], 0, 0, 0);
                    acc[mt][nt] = __builtin_amdgcn_mfma_f32_16x16x32_bf16(a1[mt], b0[nt], acc[mt][nt], 0, 0, 0);
                }
        } else {
#pragma unroll
            for (int mt = 0; mt < 4; ++mt)
#pragma unroll
                for (int nt = 0; nt < 4; ++nt)
                    acc[mt][nt] = __builtin_amdgcn_mfma_f32_16x16x32_bf16(a0[mt], b0[nt], acc[mt][nt], 0, 0, 0);
        }
    }

#pragma unroll
    for (int mt = 0; mt < 4; ++mt) {
#pragma unroll
        for (int r = 0; r < 4; ++r) {
            int oo = o0 + wr + mt * 16 + g * 4 + r;
            size_t rowbase = ((size_t)n * O + oo) * L_S;
#pragma unroll
            for (int nt = 0; nt < 4; ++nt) {
                int ll = l0 + wc + nt * 16 + c;
                if (OUT_BF16)
                    ((unsigned short*)Y)[rowbase + ll] = bf16_rn(acc[mt][nt][r]);
                else
                    ((float*)Y)[rowbase + ll] = acc[mt][nt][r];
            }
        }
    }
}

// ---------------------------------------------------------------------------
// Fused dwconv + l2norm + pack for Q/K heads (unchanged).
// ---------------------------------------------------------------------------
__global__ __launch_bounds__(256) void fused_qk2(const unsigned short* __restrict__ qkv_bf,
                                                 const float* __restrict__ w_dw,
                                                 unsigned short* __restrict__ Qb,
                                                 unsigned short* __restrict__ Kb) {
    __shared__ unsigned short rows[64 * 264];
    __shared__ float wsm[192];
    const int tid = threadIdx.x;
    const int l0  = blockIdx.x * 256;
    const int gg  = blockIdx.y;
    const int n   = blockIdx.z;
    const int head = gg & 7;
    const int ch0  = (gg < 8) ? head * 64 : 512 + head * 64;

    if (tid < 192) wsm[tid] = w_dw[ch0 * 3 + tid];

    const unsigned short* base = qkv_bf + ((size_t)n * C3 + ch0) * L_S;
    for (int f = tid; f < 2048; f += 256) {
        int e = f >> 5, s = f & 31;
        *(uint4*)&rows[e * 264 + s * 8] = *(const uint4*)&base[(size_t)e * L_S + l0 + s * 8];
    }
    if (tid < 64) {
        rows[tid * 264 + 256] = (l0 > 0) ? base[(size_t)tid * L_S + l0 - 1] : (unsigned short)0;
    } else if (tid < 128) {
        int e = tid - 64;
        rows[e * 264 + 257] = (l0 + 256 < L_S) ? base[(size_t)e * L_S + l0 + 256] : (unsigned short)0;
    }
    __syncthreads();

    const int lL = tid;
    const int iL = (lL == 0)   ? 256 : lL - 1;
    const int iR = (lL == 255) ? 257 : lL + 1;
    float y[64];
    float s = 0.f;
#pragma unroll
    for (int e = 0; e < 64; ++e) {
        float a = bf16_f(rows[e * 264 + iL]);
        float b = bf16_f(rows[e * 264 + lL]);
        float d = bf16_f(rows[e * 264 + iR]);
        float v = wsm[e * 3 + 0] * a + wsm[e * 3 + 1] * b + wsm[e * 3 + 2] * d;
        y[e] = v;
        s += v * v;
    }
    float sc = 1.0f / fmaxf(sqrtf(s), 1e-12f);

    const int l = l0 + tid;
    unsigned short* dst = ((gg < 8) ? Qb : Kb) + (size_t)(n * H_N + head) * 8 * L_S * 8;
#pragma unroll
    for (int p = 0; p < 8; ++p) {
        uint4 pk = make_uint4(pk_bf16(y[8 * p + 0] * sc, y[8 * p + 1] * sc),
                              pk_bf16(y[8 * p + 2] * sc, y[8 * p + 3] * sc),
                              pk_bf16(y[8 * p + 4] * sc, y[8 * p + 5] * sc),
                              pk_bf16(y[8 * p + 6] * sc, y[8 * p + 7] * sc));
        *(uint4*)&dst[((size_t)p * L_S + l) * 8] = pk;
    }
}

// ---------------------------------------------------------------------------
// Fused dwconv + pack for V heads (unchanged).
// ---------------------------------------------------------------------------
__global__ __launch_bounds__(256) void fused_v2(const unsigned short* __restrict__ qkv_bf,
                                                const float* __restrict__ w_dw,
                                                unsigned short* __restrict__ Vb) {
    const int tid = threadIdx.x;
    const int e   = tid & 63;
    const int jp  = blockIdx.x * 4 + (tid >> 6);
    const int h   = blockIdx.y;
    const int n   = blockIdx.z;
    const int ch  = 1024 + h * 64 + e;
    const unsigned short* row = qkv_bf + ((size_t)n * C3 + ch) * L_S;
    const int k0 = jp * 8;

    uint4 mv = *(const uint4*)&row[k0];
    unsigned int lw = (jp > 0)   ? *(const unsigned int*)&row[k0 - 2] : 0u;
    unsigned int rw = (jp < 255) ? *(const unsigned int*)&row[k0 + 8] : 0u;

    float v[10];
    v[0] = bf16_f((unsigned short)(lw >> 16));
    v[1] = bf16_f((unsigned short)(mv.x & 0xFFFF));
    v[2] = bf16_f((unsigned short)(mv.x >> 16));
    v[3] = bf16_f((unsigned short)(mv.y & 0xFFFF));
    v[4] = bf16_f((unsigned short)(mv.y >> 16));
    v[5] = bf16_f((unsigned short)(mv.z & 0xFFFF));
    v[6] = bf16_f((unsigned short)(mv.z >> 16));
    v[7] = bf16_f((unsigned short)(mv.w & 0xFFFF));
    v[8] = bf16_f((unsigned short)(mv.w >> 16));
    v[9] = bf16_f((unsigned short)(rw & 0xFFFF));

    float w0 = w_dw[ch * 3 + 0], w1 = w_dw[ch * 3 + 1], w2 = w_dw[ch * 3 + 2];
    unsigned int o[4];
#pragma unroll
    for (int i = 0; i < 4; ++i) {
        float y0 = w0 * v[2 * i + 0] + w1 * v[2 * i + 1] + w2 * v[2 * i + 2];
        float y1 = w0 * v[2 * i + 1] + w1 * v[2 * i + 2] + w2 * v[2 * i + 3];
        o[i] = pk_bf16(y0, y1);
    }
    uint4 ov = make_uint4(o[0], o[1], o[2], o[3]);
    *(uint4*)&Vb[(((size_t)(n * H_N + h) * 256 + jp) * 512) + e * 8] = ov;
}

// ---------------------------------------------------------------------------
// Flash attention v8: BARRIER-FREE main loop. Every MFMA fragment is a
// contiguous 16B run in the packed global layouts, so K/V/Q frags are loaded
// directly global->VGPR (no LDS staging, no dbuf, no __syncthreads in loop).
// 4 independent waves x 32q; L1/L2 absorb the cross-wave/block re-reads.
// setprio(1) around MFMA clusters (T5: independent-wave regime).
// grid: (L/128, H, N), 256 threads.
// ---------------------------------------------------------------------------
__global__ __launch_bounds__(256, 3) void attn8(const unsigned short* __restrict__ Qb,
                                                const unsigned short* __restrict__ Kb,
                                                const unsigned short* __restrict__ Vb,
                                                const float* __restrict__ temp,
                                                unsigned short* __restrict__ aoT_hi,
                                                unsigned short* __restrict__ aoT_lo) {
    __shared__ float Ot[128 * 64];   // 32KB transpose stage (epilogue only)
    __shared__ float sm[128];

    const int tid  = threadIdx.x;
    const int lane = tid & 63;
    const int w    = tid >> 6;     // 0..3, owns q = q0 + w*32 .. +31
    const int c32  = lane & 31;
    const int h    = lane >> 5;
    const int q0   = blockIdx.x * 128;
    const int hd   = blockIdx.y;
    const int n    = blockIdx.z;

    const size_t hb = (size_t)(n * H_N + hd);
    const unsigned short* Qh = Qb + hb * 8 * L_S * 8;
    const unsigned short* Kh = Kb + hb * 8 * L_S * 8;
    const unsigned short* Vh = Vb + hb * 256 * 512;
    const float t    = temp[hd];
    const float negm = -fabsf(t);

    // Q fragments: direct 16B loads (plane es*2+h, row q0 + w*32 + c32)
    short8 qa[4];
#pragma unroll
    for (int es = 0; es < 4; ++es)
        qa[es] = *(const short8*)&Qh[((size_t)(es * 2 + h) * L_S + q0 + w * 32 + c32) * 8];

    f32x16 acc0, acc1;
#pragma unroll
    for (int i = 0; i < 16; ++i) { acc0[i] = 0.f; acc1[i] = 0.f; }
    float sumP = 0.f;

    for (int k0 = 0; k0 < L_S; k0 += 64) {
        // ---- V fragments issued early (consumed after softmax, ~500cyc away)
        short8 vb0[4], vb1[4];
#pragma unroll
        for (int ks = 0; ks < 4; ++ks) {
            const unsigned short* vrow = Vh + (size_t)((k0 >> 3) + ks * 2 + h) * 512;
            vb0[ks] = *(const short8*)&vrow[c32 * 8];
            vb1[ks] = *(const short8*)&vrow[(32 + c32) * 8];
        }

        // ---- K fragments + QK (S^T = K Q^T; lane c32 = query, rows = keys)
        f32x16 sf0, sf1;
#pragma unroll
        for (int i = 0; i < 16; ++i) { sf0[i] = 0.f; sf1[i] = 0.f; }
        short8 ka0[4], ka1[4];
#pragma unroll
        for (int es = 0; es < 4; ++es) {
            const unsigned short* krow = Kh + (size_t)(es * 2 + h) * L_S * 8;
            ka0[es] = *(const short8*)&krow[(k0 + c32) * 8];
            ka1[es] = *(const short8*)&krow[(k0 + 32 + c32) * 8];
        }
        __builtin_amdgcn_s_setprio(1);
#pragma unroll
        for (int es = 0; es < 4; ++es) {
            sf0 = __builtin_amdgcn_mfma_f32_32x32x16_bf16(ka0[es], qa[es], sf0, 0, 0, 0);
            sf1 = __builtin_amdgcn_mfma_f32_32x32x16_bf16(ka1[es], qa[es], sf1, 0, 0, 0);
        }
        __builtin_amdgcn_s_setprio(0);

        // ---- fixed-max softmax (lane-local) + in-register P assembly
        short8 pa[4];
        {
            unsigned int W_[16], R_[16];
#pragma unroll
            for (int G = 0; G < 4; ++G) {
                float p0 = __expf(fmaf(sf0[4*G+0], t, negm));
                float p1 = __expf(fmaf(sf0[4*G+1], t, negm));
                float p2 = __expf(fmaf(sf0[4*G+2], t, negm));
                float p3 = __expf(fmaf(sf0[4*G+3], t, negm));
                sumP += (p0 + p1) + (p2 + p3);
                W_[2*G]   = pk_bf16(p0, p1);
                W_[2*G+1] = pk_bf16(p2, p3);
                float u0 = __expf(fmaf(sf1[4*G+0], t, negm));
                float u1 = __expf(fmaf(sf1[4*G+1], t, negm));
                float u2 = __expf(fmaf(sf1[4*G+2], t, negm));
                float u3 = __expf(fmaf(sf1[4*G+3], t, negm));
                sumP += (u0 + u1) + (u2 + u3);
                W_[8+2*G]   = pk_bf16(u0, u1);
                W_[8+2*G+1] = pk_bf16(u2, u3);
            }
#pragma unroll
            for (int j = 0; j < 16; ++j) R_[j] = __shfl_xor(W_[j], 32);
#pragma unroll
            for (int ks = 0; ks < 4; ++ks) {
                const int bb = (ks >> 1) * 8;
                const int m4 = (ks & 1) * 4;
                unsigned int a0 = h ? R_[bb+m4+2] : W_[bb+m4+0];
                unsigned int a1 = h ? R_[bb+m4+3] : W_[bb+m4+1];
                unsigned int a2 = h ? W_[bb+m4+2] : R_[bb+m4+0];
                unsigned int a3 = h ? W_[bb+m4+3] : R_[bb+m4+1];
                uint4 pu = make_uint4(a0, a1, a2, a3);
                pa[ks] = *(short8*)&pu;
            }
        }

        // ---- O += P V
        __builtin_amdgcn_s_setprio(1);
#pragma unroll
        for (int ks = 0; ks < 4; ++ks) {
            acc0 = __builtin_amdgcn_mfma_f32_32x32x16_bf16(pa[ks], vb0[ks], acc0, 0, 0, 0);
            acc1 = __builtin_amdgcn_mfma_f32_32x32x16_bf16(pa[ks], vb1[ks], acc1, 0, 0, 0);
        }
        __builtin_amdgcn_s_setprio(0);
    }

    // ---- final denominator (other key-half lives in lane^32)
    sumP += __shfl_xor(sumP, 32);
    sm[w * 32 + c32] = 1.0f / sumP;

    float inv[16];
#pragma unroll
    for (int r = 0; r < 16; ++r) {
        int ql = (r & 3) + 8 * (r >> 2) + 4 * h;
        inv[r] = sm[w * 32 + ql];
    }

#pragma unroll
    for (int r = 0; r < 16; ++r) {
        int ql = (r & 3) + 8 * (r >> 2) + 4 * h;
        int qg = w * 32 + ql;
        Ot[qg * 64 + (c32 ^ (qg & 31))]        = acc0[r] * inv[r];
        Ot[qg * 64 + ((32 + c32) ^ (qg & 31))] = acc1[r] * inv[r];
    }
    __syncthreads();

    // ---- transposed output: aoT[n][l][d]
    for (int tt = tid; tt < 8192; tt += 256) {
        int qq = tt >> 6, e = tt & 63;
        float v = Ot[qq * 64 + (e ^ (qq & 31))];
        unsigned short hi_ = bf16_rn(v);
        unsigned short lo_ = bf16_rn(v - bf16_f(hi_));
        size_t off = ((size_t)n * L_S + q0 + qq) * D_F + hd * 64 + e;
        aoT_hi[off] = hi_;
        aoT_lo[off] = lo_;
    }
}

// ---------------------------------------------------------------------------
extern "C" void kernel_launch(void* const* d_in, const int* in_sizes, int n_in,
                              void* d_out, int out_size, void* d_ws, size_t ws_size,
                              hipStream_t stream) {
    const float* x      = (const float*)d_in[0];   // (4, 512, 2048)
    const float* w_qkv  = (const float*)d_in[1];   // (1536, 512)
    const float* w_dw   = (const float*)d_in[2];   // (1536, 3)
    const float* w_proj = (const float*)d_in[3];   // (512, 512)
    const float* temp   = (const float*)d_in[4];   // (8)
    float* out = (float*)d_out;

    const size_t WQE = (size_t)C3 * D_F;           // 786,432
    const size_t WPE = (size_t)D_F * D_F;          // 262,144

    char* ws = (char*)d_ws;
    unsigned short* qkv_bf = (unsigned short*)ws;               // 25,165,824 B
    unsigned short* Qb     = (unsigned short*)(ws + 25165824);  //  8,388,608 B
    unsigned short* Kb     = (unsigned short*)(ws + 33554432);  //  8,388,608 B
    unsigned short* Vb     = (unsigned short*)(ws + 41943040);  //  8,388,608 B
    unsigned short* xT     = (unsigned short*)(ws + 50331648);  //  8,388,608 B
    unsigned short* aoT_lo = (unsigned short*)(ws + 58720256);  //  8,388,608 B
    unsigned short* wq_hi  = (unsigned short*)(ws + 67108864);  //  1,572,864 B
    unsigned short* wq_lo  = wq_hi + WQE;
    unsigned short* wp_hi  = (unsigned short*)(ws + 70254592);  //    524,288 B
    unsigned short* wp_lo  = wp_hi + WPE;                       // ends ~71.3 MB
    unsigned short* aoT_hi = xT;   // reuse: xT consumed by QKV gemm before attn writes

    // 0) weight splits + x transpose/convert
    cvt_xT<<<dim3(L_S / 64, D_F / 64, N_B), 256, 0, stream>>>(x, xT, D_F);
    cvt_split<<<dim3((WQE / 4 + 255) / 256), 256, 0, stream>>>(w_qkv, wq_hi, wq_lo, WQE / 4);
    cvt_split<<<dim3((WPE / 4 + 255) / 256), 256, 0, stream>>>(w_proj, wp_hi, wp_lo, WPE / 4);

    // 1) QKV 1x1 conv: bf16 MFMA, gll16-staged -> bf16
    gemm_mfma2<0, 1><<<dim3(L_S / 128, C3 / 128, N_B), 256, 0, stream>>>(
        wq_hi, nullptr, xT, nullptr, qkv_bf, C3, D_F);

    // 2) fused dwconv (+l2norm) + MFMA-layout bf16 pack
    fused_qk2<<<dim3(L_S / 256, 16, N_B), 256, 0, stream>>>(qkv_bf, w_dw, Qb, Kb);
    fused_v2<<<dim3(64, H_N, N_B), 256, 0, stream>>>(qkv_bf, w_dw, Vb);

    // 3) attention (barrier-free, direct-frag) -> transposed split bf16 hi/lo
    attn8<<<dim3(L_S / 128, H_N, N_B), 256, 0, stream>>>(Qb, Kb, Vb, temp, aoT_hi, aoT_lo);

    // 4) 3-term split-bf16 proj GEMM (gll16-staged) -> fp32 out
    gemm_mfma2<1, 0><<<dim3(L_S / 128, D_F / 128, N_B), 256, 0, stream>>>(
        wp_hi, wp_lo, aoT_hi, aoT_lo, out, D_F, D_F);
}